// Round 3
// baseline (787.556 us; speedup 1.0000x reference)
//
#include <hip/hip_runtime.h>
#include <math.h>

#define NF 39
#define ND 13
#define KDIM 16
#define FEAT 260013
#define NPAIRS (NF * (NF + 1) / 2)    // 780 unordered pairs (i<=j)
#define PAIRS_PER_PASS 64             // 256 threads / 4 lanes per pair
#define PASSES ((NPAIRS + PAIRS_PER_PASS - 1) / PAIRS_PER_PASS)  // 13

// One block per sample. 4 lanes per pair; lane q loads chunk q (16B) of BOTH
// W[i][f_j] and W[j][f_i], accumulates w * <a_q, c_q>. No cross-lane ops in
// the hot loop; per-pair element offsets + weights precomputed in LDS.
// Mask algebra (reference keeps rows i<38, all j):
//   i<j<38 : 2*xm_i*xm_j ; i==j<38 : xm_i^2 ; (i,38) i<38 : xm_i*xm_38 ; (38,38): 0
__global__ __launch_bounds__(256) void ffm_kernel(
    const float* __restrict__ x,       // [B, 39]
    const float* __restrict__ W,       // [39, FEAT, 16]
    const float* __restrict__ fc_w,    // [FEAT]
    const float* __restrict__ bias,    // [1]
    const int*   __restrict__ offsets, // [39]
    float* __restrict__ out,           // [B]
    int B)
{
    __shared__ int   sf[NF];           // global feature index per field
    __shared__ float sxm[NF];          // multiplier per field
    __shared__ int   soff_ij[NPAIRS];  // element offset of W[i][f_j]
    __shared__ int   soff_ji[NPAIRS];  // element offset of W[j][f_i]
    __shared__ float sw[NPAIRS];       // pair weight
    __shared__ float sred[4];

    const int b   = blockIdx.x;
    const int tid = threadIdx.x;

    if (tid < NF) {
        float xv = x[(size_t)b * NF + tid];
        int idx  = (tid < ND) ? 0 : (int)floorf(xv);
        sf[tid]  = idx + offsets[tid];
        sxm[tid] = (tid < ND) ? xv : 1.0f;
    }
    __syncthreads();

    // Precompute per-pair offsets + weights (each thread ~3 pairs).
    for (int p = tid; p < NPAIRS; p += 256) {
        int i = 0, base = 0;
        while (p >= base + (NF - i)) { base += NF - i; ++i; }
        int j = i + (p - base);
        soff_ij[p] = (i * FEAT + sf[j]) * KDIM;
        soff_ji[p] = (j * FEAT + sf[i]) * KDIM;
        float w;
        if (i == j)          w = (i < NF - 1) ? sxm[i] * sxm[i] : 0.0f;
        else if (j < NF - 1) w = 2.0f * sxm[i] * sxm[j];
        else                 w = sxm[i] * sxm[j];   // j == 38, i < 38
        sw[p] = w;
    }
    __syncthreads();

    const int slot = tid >> 2;   // pair slot within pass (0..63)
    const int qi   = tid & 3;    // 16B chunk index within the 64B vector

    float acc = 0.0f;
    if (tid < NF) acc += fc_w[sf[tid]];   // linear term

    #pragma unroll
    for (int pass = 0; pass < PASSES; ++pass) {
        int p  = pass * PAIRS_PER_PASS + slot;
        int pc = (p < NPAIRS) ? p : (NPAIRS - 1);
        float w = (p < NPAIRS) ? sw[pc] : 0.0f;

        const float4* aij = (const float4*)(W + soff_ij[pc]);
        const float4* cji = (const float4*)(W + soff_ji[pc]);
        float4 a = aij[qi];
        float4 c = cji[qi];

        acc += w * (a.x * c.x + a.y * c.y + a.z * c.z + a.w * c.w);
    }

    // block reduction: wave64 shuffle, then LDS across 4 waves
    #pragma unroll
    for (int off = 32; off > 0; off >>= 1)
        acc += __shfl_down(acc, off, 64);
    if ((tid & 63) == 0) sred[tid >> 6] = acc;
    __syncthreads();

    if (tid == 0) {
        float z = sred[0] + sred[1] + sred[2] + sred[3] + bias[0];
        out[b] = 1.0f / (1.0f + expf(-z));
    }
}

extern "C" void kernel_launch(void* const* d_in, const int* in_sizes, int n_in,
                              void* d_out, int out_size, void* d_ws, size_t ws_size,
                              hipStream_t stream) {
    const float* x       = (const float*)d_in[0];
    const float* W       = (const float*)d_in[1];
    const float* fc_w    = (const float*)d_in[2];
    const float* bias    = (const float*)d_in[3];
    const int*   offsets = (const int*)d_in[4];

    float* out = (float*)d_out;
    const int B = in_sizes[0] / NF;

    ffm_kernel<<<B, 256, 0, stream>>>(x, W, fc_w, bias, offsets, out, B);
}